// Round 1
// baseline (575.926 us; speedup 1.0000x reference)
//
#include <hip/hip_runtime.h>

#define B_ 2
#define S_ 2048
#define E_ 1024
#define H_ 16
#define DH 64
#define MM (B_*S_)   // 4096
#define BHN (B_*H_)  // 32

typedef unsigned short u16;
typedef unsigned int u32;
typedef __attribute__((ext_vector_type(8))) __bf16 bf16x8;
typedef __attribute__((ext_vector_type(4))) float f32x4;
typedef __attribute__((ext_vector_type(8))) u16 u16x8;
typedef __attribute__((ext_vector_type(4))) u16 u16x4;

static __device__ __forceinline__ u16 f2bf(float f) {
  u32 u = __builtin_bit_cast(u32, f);
  u += 0x7fffu + ((u >> 16) & 1u);
  return (u16)(u >> 16);
}
static __device__ __forceinline__ float bf2f(u16 h) {
  return __builtin_bit_cast(float, (u32)h << 16);
}
// XOR swizzle for 128B-stride row-major LDS tiles: spreads the 16-lane
// same-column read (classic 32-way conflict, G4) across 8 16B slots.
static __device__ __forceinline__ u32 sw(u32 byte) {
  return byte ^ (((byte >> 7) & 7u) << 4);
}
static __device__ __forceinline__ void cp16(u16* lds, u32 ldsbyte, const u16* g) {
  *(u16x8*)((char*)lds + ldsbyte) = *(const u16x8*)g;
}
static __device__ __forceinline__ bf16x8 frag(const u16* lds, u32 byte) {
  return *(const bf16x8*)((const char*)lds + byte);
}
static __device__ __forceinline__ f32x4 mfma16(bf16x8 a, bf16x8 b, f32x4 c) {
  return __builtin_amdgcn_mfma_f32_16x16x32_bf16(a, b, c, 0, 0, 0);
}

// ---------------- split: f32 -> (hi, lo) bf16 ----------------
__global__ void split_kernel(const float* __restrict__ src, u16* __restrict__ hi,
                             u16* __restrict__ lo, int n4) {
  int i = blockIdx.x * blockDim.x + threadIdx.x;
  int stride = gridDim.x * blockDim.x;
  for (; i < n4; i += stride) {
    float4 v = ((const float4*)src)[i];
    u16x4 h, l;
    h.x = f2bf(v.x); l.x = f2bf(v.x - bf2f(h.x));
    h.y = f2bf(v.y); l.y = f2bf(v.y - bf2f(h.y));
    h.z = f2bf(v.z); l.z = f2bf(v.z - bf2f(h.z));
    h.w = f2bf(v.w); l.w = f2bf(v.w - bf2f(h.w));
    ((u16x4*)hi)[i] = h;
    ((u16x4*)lo)[i] = l;
  }
}

// ---------------- projection GEMM ----------------
// C[m,e] = sum_k x[m,k] W[e,k] + bias[e], via virtual K'=3072:
//   [x_hi | x_hi | x_lo] . [W_hi | W_lo | W_hi]
// mode 0/1: write hi/lo bf16 in (B,H,S,Dh) layout. mode 2: write bf16 V^T (B,H,Dh,S).
struct ProjArgs {
  const u16* xhi; const u16* xlo; const u16* whi; const u16* wlo;
  const float* bias; u16* ohi; u16* olo; int mode;
};

__global__ __launch_bounds__(256, 2) void proj_gemm(ProjArgs a0, ProjArgs a1, ProjArgs a2) {
  ProjArgs A = (blockIdx.z == 0) ? a0 : (blockIdx.z == 1) ? a1 : a2;
  __shared__ u16 As[128 * 64];
  __shared__ u16 Bs[128 * 64];
  const int t = threadIdx.x;
  const int l = t & 63, wid = t >> 6;
  const int g = l >> 4, ln = l & 15;
  const int wm = wid >> 1, wn = wid & 1;
  const int m0 = blockIdx.y * 128, e0 = blockIdx.x * 128;

  f32x4 acc[4][4] = {};

  for (int kt = 0; kt < 48; ++kt) {
    int kp = kt * 64;
    const u16* asrc = (kp < 2048) ? A.xhi : A.xlo;
    const u16* bsrc = (kp < 1024 || kp >= 2048) ? A.whi : A.wlo;
    int kc = kp & 1023;
#pragma unroll
    for (int i = 0; i < 4; ++i) {
      int c = t + 256 * i;          // 1024 chunks of 16B per tile
      int row = c >> 3;
      u32 lb = sw((u32)c * 16);
      cp16(As, lb, asrc + (size_t)(m0 + row) * 1024 + kc + (c & 7) * 8);
      cp16(Bs, lb, bsrc + (size_t)(e0 + row) * 1024 + kc + (c & 7) * 8);
    }
    __syncthreads();
#pragma unroll
    for (int ks = 0; ks < 2; ++ks) {
      bf16x8 af[4], bfv[4];
#pragma unroll
      for (int i = 0; i < 4; ++i) {
        u32 ar = (u32)(wm * 64 + i * 16 + ln);
        af[i] = frag(As, sw(ar * 128 + g * 16 + ks * 64));
        u32 br = (u32)(wn * 64 + i * 16 + ln);
        bfv[i] = frag(Bs, sw(br * 128 + g * 16 + ks * 64));
      }
#pragma unroll
      for (int i = 0; i < 4; ++i)
#pragma unroll
        for (int j = 0; j < 4; ++j)
          acc[i][j] = mfma16(af[i], bfv[j], acc[i][j]);
    }
    __syncthreads();
  }

#pragma unroll
  for (int i = 0; i < 4; ++i) {
#pragma unroll
    for (int j = 0; j < 4; ++j) {
#pragma unroll
      for (int r = 0; r < 4; ++r) {
        int m = m0 + wm * 64 + i * 16 + g * 4 + r;
        int e = e0 + wn * 64 + j * 16 + ln;
        float v = acc[i][j][r] + A.bias[e];
        int b = m >> 11, s = m & 2047;
        int h = e >> 6, d = e & 63;
        if (A.mode < 2) {
          size_t idx = ((size_t)((b * 16 + h) * 2048 + s)) * 64 + d;
          u16 hv = f2bf(v);
          A.ohi[idx] = hv;
          A.olo[idx] = f2bf(v - bf2f(hv));
        } else {
          size_t idx = ((size_t)((b * 16 + h) * 64 + d)) * 2048 + s;
          A.ohi[idx] = f2bf(v);
        }
      }
    }
  }
}

// ---------------- attention ----------------
// grid: (S/128 q-tiles, B*H). 4 waves in 2x2 (wq, wk).
// No-max softmax: Z = sum(exp(s)) over valid keys; P = exp(s)*dmask; out = P.V / Z.
__global__ __launch_bounds__(256, 2) void attn_kernel(
    const u16* __restrict__ qhi, const u16* __restrict__ qlo,
    const u16* __restrict__ khi, const u16* __restrict__ klo,
    const u16* __restrict__ vt, const int* __restrict__ amask,
    const float* __restrict__ dmask, float* __restrict__ out) {
  __shared__ u16 Ksh[64 * 64];
  __shared__ u16 Ksl[64 * 64];
  __shared__ u16 Vs[64 * 64];     // [d][key] (V^T tile)
  __shared__ u16 Ps[128 * 64];    // [q][key]; also Q staging buffer
  __shared__ float Zb[128][2];

  const int t = threadIdx.x, l = t & 63, wid = t >> 6;
  const int g = l >> 4, ln = l & 15;
  const int wq = wid >> 1, wk = wid & 1;
  const int bh = blockIdx.y, b = bh >> 4;
  const int q0 = blockIdx.x * 128;
  const size_t qbase = ((size_t)bh * 2048 + q0) * 64;

  // Hoist Q fragments (hi & lo) into registers via LDS.
  bf16x8 aQh[4][2], aQl[4][2];
#pragma unroll
  for (int pass = 0; pass < 2; ++pass) {
    const u16* src = (pass ? qlo : qhi) + qbase;
#pragma unroll
    for (int i = 0; i < 4; ++i) {
      int c = t + 256 * i;
      cp16(Ps, sw((u32)c * 16), src + c * 8);
    }
    __syncthreads();
#pragma unroll
    for (int i = 0; i < 4; ++i)
#pragma unroll
      for (int ks = 0; ks < 2; ++ks) {
        u32 row = (u32)(wq * 64 + i * 16 + ln);
        bf16x8 f = frag(Ps, sw(row * 128 + g * 16 + ks * 64));
        if (pass) aQl[i][ks] = f; else aQh[i][ks] = f;
      }
    __syncthreads();
  }

  f32x4 O[4][2] = {};
  float Zp[4][4] = {};

  for (int kt = 0; kt < 32; ++kt) {
    int k0 = kt * 64;
    const size_t kbase = ((size_t)bh * 2048 + k0) * 64;
    // stage K hi/lo (8KB each) and V^T tile (8KB)
#pragma unroll
    for (int i = 0; i < 2; ++i) {
      int c = t + 256 * i;          // 0..511
      u32 lb = sw((u32)c * 16);
      cp16(Ksh, lb, khi + kbase + c * 8);
      cp16(Ksl, lb, klo + kbase + c * 8);
      int row = c >> 3;
      cp16(Vs, lb, vt + ((size_t)bh * 64 + row) * 2048 + k0 + (c & 7) * 8);
    }
    __syncthreads();

    // QK^T (3-term split)
    f32x4 sc[4][2] = {};
#pragma unroll
    for (int ks = 0; ks < 2; ++ks) {
      bf16x8 bkh[2], bkl[2];
#pragma unroll
      for (int j = 0; j < 2; ++j) {
        u32 key = (u32)(wk * 32 + j * 16 + ln);
        u32 byt = sw(key * 128 + g * 16 + ks * 64);
        bkh[j] = frag(Ksh, byt);
        bkl[j] = frag(Ksl, byt);
      }
#pragma unroll
      for (int i = 0; i < 4; ++i)
#pragma unroll
        for (int j = 0; j < 2; ++j) {
          sc[i][j] = mfma16(aQh[i][ks], bkh[j], sc[i][j]);
          sc[i][j] = mfma16(aQh[i][ks], bkl[j], sc[i][j]);
          sc[i][j] = mfma16(aQl[i][ks], bkh[j], sc[i][j]);
        }
    }

    // pad mask -> exp -> Z accumulate -> dropout -> P(bf16) to LDS
#pragma unroll
    for (int j = 0; j < 2; ++j) {
      int kloc = wk * 32 + j * 16 + ln;
      int kg = k0 + kloc;
      int ok = amask[b * 2048 + kg];
#pragma unroll
      for (int i = 0; i < 4; ++i) {
#pragma unroll
        for (int r = 0; r < 4; ++r) {
          int qloc = wq * 64 + i * 16 + g * 4 + r;
          float e = ok ? __expf(sc[i][j][r]) : 0.f;
          Zp[i][r] += e;
          float dm = dmask[((size_t)bh * 2048 + (q0 + qloc)) * 2048 + kg];
          *(u16*)((char*)Ps + sw((u32)(qloc * 128 + kloc * 2))) = f2bf(e * dm);
        }
      }
    }
    __syncthreads();

    // PV
#pragma unroll
    for (int ks = 0; ks < 2; ++ks) {
      bf16x8 aP[4], bV[2];
#pragma unroll
      for (int i = 0; i < 4; ++i) {
        u32 qr = (u32)(wq * 64 + i * 16 + ln);
        aP[i] = frag(Ps, sw(qr * 128 + g * 16 + ks * 64));
      }
#pragma unroll
      for (int j = 0; j < 2; ++j) {
        u32 d = (u32)(wk * 32 + j * 16 + ln);
        bV[j] = frag(Vs, sw(d * 128 + g * 16 + ks * 64));
      }
#pragma unroll
      for (int i = 0; i < 4; ++i)
#pragma unroll
        for (int j = 0; j < 2; ++j)
          O[i][j] = mfma16(aP[i], bV[j], O[i][j]);
    }
    __syncthreads();
  }

  // reduce Z across the 16 column-lanes, combine the two k-half waves via LDS
#pragma unroll
  for (int i = 0; i < 4; ++i)
#pragma unroll
    for (int r = 0; r < 4; ++r) {
      float z = Zp[i][r];
#pragma unroll
      for (int w = 1; w < 16; w <<= 1) z += __shfl_xor(z, w, 64);
      if (ln == 0) Zb[wq * 64 + i * 16 + g * 4 + r][wk] = z;
    }
  __syncthreads();

#pragma unroll
  for (int i = 0; i < 4; ++i) {
#pragma unroll
    for (int r = 0; r < 4; ++r) {
      int qloc = wq * 64 + i * 16 + g * 4 + r;
      float rz = 1.f / (Zb[qloc][0] + Zb[qloc][1]);
#pragma unroll
      for (int j = 0; j < 2; ++j) {
        int d = wk * 32 + j * 16 + ln;
        out[((size_t)bh * 2048 + (q0 + qloc)) * 64 + d] = O[i][j][r] * rz;
      }
    }
  }
}

// ---------------- host ----------------
extern "C" void kernel_launch(void* const* d_in, const int* in_sizes, int n_in,
                              void* d_out, int out_size, void* d_ws, size_t ws_size,
                              hipStream_t stream) {
  const float* query = (const float*)d_in[0];
  const float* keyt  = (const float*)d_in[1];
  const float* value = (const float*)d_in[2];
  const int*   amask = (const int*)d_in[3];
  const float* dmask = (const float*)d_in[4];
  const float* Wq = (const float*)d_in[5];
  const float* bq = (const float*)d_in[6];
  const float* Wk = (const float*)d_in[7];
  const float* bk = (const float*)d_in[8];
  const float* Wv = (const float*)d_in[9];
  const float* bv = (const float*)d_in[10];

  char* ws = (char*)d_ws;
  size_t off = 0;
  auto alloc = [&](size_t bytes) {
    char* p = ws + off;
    off += (bytes + 255) & ~(size_t)255;
    return p;
  };
  const size_t XB = (size_t)MM * E_ * sizeof(u16);   // 8 MB
  const size_t WB = (size_t)E_ * E_ * sizeof(u16);   // 2 MB

  u16 *xh[3], *xl[3], *wh[3], *wl[3];
  for (int i = 0; i < 3; ++i) { xh[i] = (u16*)alloc(XB); xl[i] = (u16*)alloc(XB); }
  for (int i = 0; i < 3; ++i) { wh[i] = (u16*)alloc(WB); wl[i] = (u16*)alloc(WB); }
  u16* q_hi = (u16*)alloc(XB);
  u16* q_lo = (u16*)alloc(XB);
  u16* k_hi = (u16*)alloc(XB);
  u16* k_lo = (u16*)alloc(XB);
  u16* v_t  = (u16*)alloc(XB);
  if (off > ws_size) return;  // workspace too small: bail (bench will flag)

  const float* xs[3] = {query, keyt, value};
  const float* wsrc[3] = {Wq, Wk, Wv};
  for (int i = 0; i < 3; ++i) {
    split_kernel<<<1024, 256, 0, stream>>>(xs[i], xh[i], xl[i], MM * E_ / 4);
    split_kernel<<<512, 256, 0, stream>>>(wsrc[i], wh[i], wl[i], E_ * E_ / 4);
  }

  ProjArgs pa[3] = {
      {xh[0], xl[0], wh[0], wl[0], bq, q_hi, q_lo, 0},
      {xh[1], xl[1], wh[1], wl[1], bk, k_hi, k_lo, 1},
      {xh[2], xl[2], wh[2], wl[2], bv, v_t, nullptr, 2},
  };
  proj_gemm<<<dim3(E_ / 128, MM / 128, 3), 256, 0, stream>>>(pa[0], pa[1], pa[2]);

  attn_kernel<<<dim3(S_ / 128, BHN), 256, 0, stream>>>(
      q_hi, q_lo, k_hi, k_lo, v_t, amask, dmask, (float*)d_out);
}

// Round 2
// 328.724 us; speedup vs baseline: 1.7520x; 1.7520x over previous
//
#include <hip/hip_runtime.h>

#define B_ 2
#define S_ 2048
#define E_ 1024
#define H_ 16
#define DH 64
#define MM (B_*S_)   // 4096
#define BHN (B_*H_)  // 32

typedef unsigned short u16;
typedef unsigned int u32;
typedef __attribute__((ext_vector_type(8))) __bf16 bf16x8;
typedef __attribute__((ext_vector_type(4))) float f32x4;
typedef __attribute__((ext_vector_type(8))) u16 u16x8;
typedef __attribute__((ext_vector_type(4))) u16 u16x4;

static __device__ __forceinline__ u16 f2bf(float f) {
  u32 u = __builtin_bit_cast(u32, f);
  u += 0x7fffu + ((u >> 16) & 1u);
  return (u16)(u >> 16);
}
static __device__ __forceinline__ float bf2f(u16 h) {
  return __builtin_bit_cast(float, (u32)h << 16);
}
// XOR swizzle for 128B-stride row-major LDS tiles (round-1 validated: 0 conflicts).
static __device__ __forceinline__ u32 sw(u32 byte) {
  return byte ^ (((byte >> 7) & 7u) << 4);
}
static __device__ __forceinline__ void cp16(u16* lds, u32 ldsbyte, const u16* g) {
  *(u16x8*)((char*)lds + ldsbyte) = *(const u16x8*)g;
}
static __device__ __forceinline__ bf16x8 frag(const u16* lds, u32 byte) {
  return *(const bf16x8*)((const char*)lds + byte);
}
static __device__ __forceinline__ f32x4 mfma16(bf16x8 a, bf16x8 b, f32x4 c) {
  return __builtin_amdgcn_mfma_f32_16x16x32_bf16(a, b, c, 0, 0, 0);
}

// ---------------- split: f32 -> (hi, lo) bf16, 3 arrays per launch ----------------
__global__ void split3_kernel(const float* __restrict__ s0, u16* __restrict__ h0, u16* __restrict__ l0,
                              const float* __restrict__ s1, u16* __restrict__ h1, u16* __restrict__ l1,
                              const float* __restrict__ s2, u16* __restrict__ h2, u16* __restrict__ l2,
                              int n4) {
  const float* src = (blockIdx.z == 0) ? s0 : (blockIdx.z == 1) ? s1 : s2;
  u16* hi = (blockIdx.z == 0) ? h0 : (blockIdx.z == 1) ? h1 : h2;
  u16* lo = (blockIdx.z == 0) ? l0 : (blockIdx.z == 1) ? l1 : l2;
  int i = blockIdx.x * blockDim.x + threadIdx.x;
  int stride = gridDim.x * blockDim.x;
  for (; i < n4; i += stride) {
    float4 v = ((const float4*)src)[i];
    u16x4 h, l;
    h.x = f2bf(v.x); l.x = f2bf(v.x - bf2f(h.x));
    h.y = f2bf(v.y); l.y = f2bf(v.y - bf2f(h.y));
    h.z = f2bf(v.z); l.z = f2bf(v.z - bf2f(h.z));
    h.w = f2bf(v.w); l.w = f2bf(v.w - bf2f(h.w));
    ((u16x4*)hi)[i] = h;
    ((u16x4*)lo)[i] = l;
  }
}

// ---------------- projection GEMM (unchanged structure, packed V^T store) ----------------
struct ProjArgs {
  const u16* xhi; const u16* xlo; const u16* whi; const u16* wlo;
  const float* bias; u16* ohi; u16* olo; int mode;
};

__global__ __launch_bounds__(256, 2) void proj_gemm(ProjArgs a0, ProjArgs a1, ProjArgs a2) {
  ProjArgs A = (blockIdx.z == 0) ? a0 : (blockIdx.z == 1) ? a1 : a2;
  __shared__ u16 As[128 * 64];
  __shared__ u16 Bs[128 * 64];
  const int t = threadIdx.x;
  const int l = t & 63, wid = t >> 6;
  const int g = l >> 4, ln = l & 15;
  const int wm = wid >> 1, wn = wid & 1;
  const int m0 = blockIdx.y * 128, e0 = blockIdx.x * 128;

  f32x4 acc[4][4] = {};

  for (int kt = 0; kt < 48; ++kt) {
    int kp = kt * 64;
    const u16* asrc = (kp < 2048) ? A.xhi : A.xlo;
    const u16* bsrc = (kp < 1024 || kp >= 2048) ? A.whi : A.wlo;
    int kc = kp & 1023;
#pragma unroll
    for (int i = 0; i < 4; ++i) {
      int c = t + 256 * i;
      int row = c >> 3;
      u32 lb = sw((u32)c * 16);
      cp16(As, lb, asrc + (size_t)(m0 + row) * 1024 + kc + (c & 7) * 8);
      cp16(Bs, lb, bsrc + (size_t)(e0 + row) * 1024 + kc + (c & 7) * 8);
    }
    __syncthreads();
#pragma unroll
    for (int ks = 0; ks < 2; ++ks) {
      bf16x8 af[4], bfv[4];
#pragma unroll
      for (int i = 0; i < 4; ++i) {
        u32 ar = (u32)(wm * 64 + i * 16 + ln);
        af[i] = frag(As, sw(ar * 128 + g * 16 + ks * 64));
        u32 br = (u32)(wn * 64 + i * 16 + ln);
        bfv[i] = frag(Bs, sw(br * 128 + g * 16 + ks * 64));
      }
#pragma unroll
      for (int i = 0; i < 4; ++i)
#pragma unroll
        for (int j = 0; j < 4; ++j)
          acc[i][j] = mfma16(af[i], bfv[j], acc[i][j]);
    }
    __syncthreads();
  }

#pragma unroll
  for (int i = 0; i < 4; ++i) {
#pragma unroll
    for (int j = 0; j < 4; ++j) {
      int e = e0 + wn * 64 + j * 16 + ln;
      int h = e >> 6, d = e & 63;
      float bias = A.bias[e];
      if (A.mode < 2) {
#pragma unroll
        for (int r = 0; r < 4; ++r) {
          int m = m0 + wm * 64 + i * 16 + g * 4 + r;
          float v = acc[i][j][r] + bias;
          int b = m >> 11, s = m & 2047;
          size_t idx = ((size_t)((b * 16 + h) * 2048 + s)) * 64 + d;
          u16 hv = f2bf(v);
          A.ohi[idx] = hv;
          A.olo[idx] = f2bf(v - bf2f(hv));
        }
      } else {
        int m = m0 + wm * 64 + i * 16 + g * 4;
        int b = m >> 11, s = m & 2047;
        u16x4 pv;
#pragma unroll
        for (int r = 0; r < 4; ++r) pv[r] = f2bf(acc[i][j][r] + bias);
        size_t idx = ((size_t)((b * 16 + h) * 64 + d)) * 2048 + s;
        *(u16x4*)(A.ohi + idx) = pv;
      }
    }
  }
}

// ---------------- attention (swapped orientation) ----------------
// St = K.Q^T per tile: k rows, q cols. Each wave owns a 16-q slab, full 64-k tile.
// Scores frag: lane(g,ln): q=ln, k=i*16+4g+r -> dmask float4 loads, P packs to b64.
// PV: O^T = V^T . P^T, per-wave private Ps slab (no exp->PV barrier).
__global__ __launch_bounds__(256, 4) void attn_kernel(
    const u16* __restrict__ qhi, const u16* __restrict__ qlo,
    const u16* __restrict__ khi, const u16* __restrict__ klo,
    const u16* __restrict__ vt, const int* __restrict__ amask,
    const float* __restrict__ dmask, float* __restrict__ out) {
  __shared__ u16 Ksh[64 * 64];
  __shared__ u16 Ksl[64 * 64];
  __shared__ u16 Vs[64 * 64];       // [d][k]
  __shared__ u16 Ps[4 * 16 * 64];   // per-wave [16 q][64 k]

  const int t = threadIdx.x, l = t & 63, wid = t >> 6;
  const int g = l >> 4, ln = l & 15;

  // XCD-aware swizzle: 1024 blocks, 8 XCDs, 128 blocks/XCD -> 4 bh per XCD.
  int bid = blockIdx.y * 32 + blockIdx.x;
  int sid = (bid & 7) * 128 + (bid >> 3);
  const int qt = sid & 31, bh = sid >> 5, b = bh >> 4;
  const int q0 = qt * 64;
  const int qrow = q0 + wid * 16 + ln;
  const size_t qg = ((size_t)bh * 2048 + qrow) * 64;

  // Q fragments (B-operand): lane(g,ln): q=ln(+slab), d = ks*32+g*8+j. Direct global.
  bf16x8 qh[2], ql[2];
#pragma unroll
  for (int ks = 0; ks < 2; ++ks) {
    qh[ks] = *(const bf16x8*)(qhi + qg + ks * 32 + g * 8);
    ql[ks] = *(const bf16x8*)(qlo + qg + ks * 32 + g * 8);
  }

  f32x4 O[4] = {};
  float Zacc = 0.f;
  const size_t dmrow = ((size_t)bh * 2048 + qrow) * 2048;
  const u32 psbase = (u32)(wid * 2048 + ln * 128);

  for (int kt = 0; kt < 32; ++kt) {
    const int k0 = kt * 64;
    // dmask + pad-mask loads: independent of everything, issue first.
    float4 dm[4]; int4 ok[4];
#pragma unroll
    for (int i = 0; i < 4; ++i) {
      dm[i] = *(const float4*)(dmask + dmrow + k0 + i * 16 + 4 * g);
      ok[i] = *(const int4*)(amask + b * 2048 + k0 + i * 16 + 4 * g);
    }

    if (kt) __syncthreads();   // all waves done reading Ks/Vs of prev tile
    const size_t kbase = ((size_t)bh * 2048 + k0) * 64;
#pragma unroll
    for (int i = 0; i < 2; ++i) {
      int c = t + 256 * i;     // 512 chunks of 16B
      u32 lb = sw((u32)c * 16);
      int row = c >> 3;
      cp16(Ksh, lb, khi + kbase + c * 8);
      cp16(Ksl, lb, klo + kbase + c * 8);
      cp16(Vs, lb, vt + ((size_t)bh * 64 + row) * 2048 + k0 + (c & 7) * 8);
    }
    __syncthreads();

    // QK^T (3-term split): A = K rows, B = Q.
    f32x4 sc[4] = {};
#pragma unroll
    for (int ks = 0; ks < 2; ++ks) {
#pragma unroll
      for (int i = 0; i < 4; ++i) {
        u32 byt = sw((u32)((i * 16 + ln) * 128 + ks * 64 + g * 16));
        bf16x8 akh = frag(Ksh, byt);
        bf16x8 akl = frag(Ksl, byt);
        sc[i] = mfma16(akh, qh[ks], sc[i]);
        sc[i] = mfma16(akh, ql[ks], sc[i]);
        sc[i] = mfma16(akl, qh[ks], sc[i]);
      }
    }

    // pad mask -> exp -> Z -> dropout -> packed P^T write (own slab, no barrier)
#pragma unroll
    for (int i = 0; i < 4; ++i) {
      float e0 = ok[i].x ? __expf(sc[i][0]) : 0.f;
      float e1 = ok[i].y ? __expf(sc[i][1]) : 0.f;
      float e2 = ok[i].z ? __expf(sc[i][2]) : 0.f;
      float e3 = ok[i].w ? __expf(sc[i][3]) : 0.f;
      Zacc += (e0 + e1) + (e2 + e3);
      u16x4 p;
      p.x = f2bf(e0 * dm[i].x);
      p.y = f2bf(e1 * dm[i].y);
      p.z = f2bf(e2 * dm[i].z);
      p.w = f2bf(e3 * dm[i].w);
      *(u16x4*)((char*)Ps + sw(psbase + i * 32 + g * 8)) = p;
    }

    // PV: O^T = V^T . P^T. A = V^T rows d, B = P^T (col=q=ln, k=ks*32+g*8+j).
#pragma unroll
    for (int ks = 0; ks < 2; ++ks) {
      bf16x8 bP = frag(Ps, sw(psbase + ks * 64 + g * 16));
#pragma unroll
      for (int id = 0; id < 4; ++id) {
        bf16x8 aV = frag(Vs, sw((u32)((id * 16 + ln) * 128 + ks * 64 + g * 16)));
        O[id] = mfma16(aV, bP, O[id]);
      }
    }
  }

  // Z: sum over k held across g groups (lane bits 4-5)
  float z = Zacc;
  z += __shfl_xor(z, 16, 64);
  z += __shfl_xor(z, 32, 64);
  float rz = 1.f / z;

  // O^T frag: lane(g,ln): q=ln, d=id*16+4g+r -> float4 stores
#pragma unroll
  for (int id = 0; id < 4; ++id) {
    float4 o;
    o.x = O[id][0] * rz; o.y = O[id][1] * rz;
    o.z = O[id][2] * rz; o.w = O[id][3] * rz;
    *(float4*)(out + qg + id * 16 + 4 * g) = o;
  }
}

// ---------------- host ----------------
extern "C" void kernel_launch(void* const* d_in, const int* in_sizes, int n_in,
                              void* d_out, int out_size, void* d_ws, size_t ws_size,
                              hipStream_t stream) {
  const float* query = (const float*)d_in[0];
  const float* keyt  = (const float*)d_in[1];
  const float* value = (const float*)d_in[2];
  const int*   amask = (const int*)d_in[3];
  const float* dmask = (const float*)d_in[4];
  const float* Wq = (const float*)d_in[5];
  const float* bq = (const float*)d_in[6];
  const float* Wk = (const float*)d_in[7];
  const float* bk = (const float*)d_in[8];
  const float* Wv = (const float*)d_in[9];
  const float* bv = (const float*)d_in[10];

  char* ws = (char*)d_ws;
  size_t off = 0;
  auto alloc = [&](size_t bytes) {
    char* p = ws + off;
    off += (bytes + 255) & ~(size_t)255;
    return p;
  };
  const size_t XB = (size_t)MM * E_ * sizeof(u16);   // 8 MB
  const size_t WB = (size_t)E_ * E_ * sizeof(u16);   // 2 MB

  u16 *xh[3], *xl[3], *wh[3], *wl[3];
  for (int i = 0; i < 3; ++i) { xh[i] = (u16*)alloc(XB); xl[i] = (u16*)alloc(XB); }
  for (int i = 0; i < 3; ++i) { wh[i] = (u16*)alloc(WB); wl[i] = (u16*)alloc(WB); }
  u16* q_hi = (u16*)alloc(XB);
  u16* q_lo = (u16*)alloc(XB);
  u16* k_hi = (u16*)alloc(XB);
  u16* k_lo = (u16*)alloc(XB);
  u16* v_t  = (u16*)alloc(XB);
  if (off > ws_size) return;

  split3_kernel<<<dim3(1024, 1, 3), 256, 0, stream>>>(
      query, xh[0], xl[0], keyt, xh[1], xl[1], value, xh[2], xl[2], MM * E_ / 4);
  split3_kernel<<<dim3(256, 1, 3), 256, 0, stream>>>(
      Wq, wh[0], wl[0], Wk, wh[1], wl[1], Wv, wh[2], wl[2], E_ * E_ / 4);

  ProjArgs pa[3] = {
      {xh[0], xl[0], wh[0], wl[0], bq, q_hi, q_lo, 0},
      {xh[1], xl[1], wh[1], wl[1], bk, k_hi, k_lo, 1},
      {xh[2], xl[2], wh[2], wl[2], bv, v_t, nullptr, 2},
  };
  proj_gemm<<<dim3(E_ / 128, MM / 128, 3), 256, 0, stream>>>(pa[0], pa[1], pa[2]);

  attn_kernel<<<dim3(32, 32), 256, 0, stream>>>(
      q_hi, q_lo, k_hi, k_lo, v_t, amask, dmask, (float*)d_out);
}

// Round 3
// 306.396 us; speedup vs baseline: 1.8797x; 1.0729x over previous
//
#include <hip/hip_runtime.h>

#define B_ 2
#define S_ 2048
#define E_ 1024
#define H_ 16
#define DH 64
#define MM (B_*S_)   // 4096
#define BHN (B_*H_)  // 32

typedef unsigned short u16;
typedef unsigned int u32;
typedef __attribute__((ext_vector_type(8))) __bf16 bf16x8;
typedef __attribute__((ext_vector_type(4))) float f32x4;
typedef __attribute__((ext_vector_type(8))) u16 u16x8;
typedef __attribute__((ext_vector_type(4))) u16 u16x4;

static __device__ __forceinline__ u16 f2bf(float f) {
  u32 u = __builtin_bit_cast(u32, f);
  u += 0x7fffu + ((u >> 16) & 1u);
  return (u16)(u >> 16);
}
static __device__ __forceinline__ float bf2f(u16 h) {
  return __builtin_bit_cast(float, (u32)h << 16);
}
// XOR swizzle for 128B-stride row-major LDS tiles (attn only; 0 conflicts measured).
static __device__ __forceinline__ u32 sw(u32 byte) {
  return byte ^ (((byte >> 7) & 7u) << 4);
}
static __device__ __forceinline__ bf16x8 frag(const u16* lds, u32 byte) {
  return *(const bf16x8*)((const char*)lds + byte);
}
static __device__ __forceinline__ f32x4 mfma16(bf16x8 a, bf16x8 b, f32x4 c) {
  return __builtin_amdgcn_mfma_f32_16x16x32_bf16(a, b, c, 0, 0, 0);
}
static __device__ __forceinline__ void gload_lds16(const u16* g, u16* lds_base) {
  __builtin_amdgcn_global_load_lds(
      (const __attribute__((address_space(1))) u32*)g,
      (__attribute__((address_space(3))) u32*)lds_base, 16, 0, 0);
}

// ---------------- split: f32 -> (hi, lo) bf16, 6 tensors in one launch ----------------
struct SplitArg { const float* s; u16* h; u16* l; int n4; };

__global__ void split6_kernel(SplitArg a0, SplitArg a1, SplitArg a2,
                              SplitArg a3, SplitArg a4, SplitArg a5) {
  SplitArg A = (blockIdx.z == 0) ? a0 : (blockIdx.z == 1) ? a1 : (blockIdx.z == 2) ? a2
             : (blockIdx.z == 3) ? a3 : (blockIdx.z == 4) ? a4 : a5;
  int i = blockIdx.x * blockDim.x + threadIdx.x;
  int stride = gridDim.x * blockDim.x;
  for (; i < A.n4; i += stride) {
    float4 v = ((const float4*)A.s)[i];
    u16x4 h, l;
    h.x = f2bf(v.x); l.x = f2bf(v.x - bf2f(h.x));
    h.y = f2bf(v.y); l.y = f2bf(v.y - bf2f(h.y));
    h.z = f2bf(v.z); l.z = f2bf(v.z - bf2f(h.z));
    h.w = f2bf(v.w); l.w = f2bf(v.w - bf2f(h.w));
    ((u16x4*)A.h)[i] = h;
    ((u16x4*)A.l)[i] = l;
  }
}

// ---------------- projection GEMM: m97 structure ----------------
// global_load_lds width-16, LINEAR LDS (swizzle is null in 2-barrier regime).
// mode 0/1: hi/lo bf16 out, (B,H,S,Dh). mode 2: bf16 V^T out (B,H,Dh,S), 2-term split.
struct ProjArgs {
  const u16* xhi; const u16* xlo; const u16* whi; const u16* wlo;
  const float* bias; u16* ohi; u16* olo; int mode;
};

__global__ __launch_bounds__(256, 2) void proj_gemm(ProjArgs a0, ProjArgs a1, ProjArgs a2) {
  ProjArgs A = (blockIdx.z == 0) ? a0 : (blockIdx.z == 1) ? a1 : a2;
  __shared__ u16 As[128 * 64];
  __shared__ u16 Bs[128 * 64];
  const int t = threadIdx.x;
  const int l = t & 63, wid = t >> 6;
  const int g = l >> 4, ln = l & 15;
  const int wm = wid >> 1, wn = wid & 1;
  // XCD-aware swizzle within each z-slice (256 blocks, 256%8==0 -> bijective).
  int bid = blockIdx.y * 8 + blockIdx.x;
  int sid = (bid & 7) * 32 + (bid >> 3);
  const int m0 = (sid >> 3) * 128, e0 = (sid & 7) * 128;

  f32x4 acc[4][4] = {};
  const int nkt = (A.mode == 2) ? 32 : 48;   // V: 2-term split only

  for (int kt = 0; kt < nkt; ++kt) {
    int kp = kt * 64;
    const u16* asrc = (kp < 2048) ? A.xhi : A.xlo;
    const u16* bsrc = (kp < 1024 || kp >= 2048) ? A.whi : A.wlo;
    int kc = kp & 1023;
    // stage: 1024 16B-chunks per tile; wave wid takes rounds wid*4..wid*4+3.
#pragma unroll
    for (int r = 0; r < 4; ++r) {
      int cr = wid * 4 + r;                  // 64-chunk group index 0..15
      int row = cr * 8 + (l >> 3);
      int col = (l & 7) * 8;
      gload_lds16(asrc + (size_t)(m0 + row) * 1024 + kc + col, As + cr * 512);
      gload_lds16(bsrc + (size_t)(e0 + row) * 1024 + kc + col, Bs + cr * 512);
    }
    __syncthreads();
#pragma unroll
    for (int ks = 0; ks < 2; ++ks) {
      bf16x8 af[4], bfv[4];
#pragma unroll
      for (int i = 0; i < 4; ++i) {
        af[i] = frag(As, (u32)(wm * 64 + i * 16 + ln) * 128 + ks * 64 + g * 16);
        bfv[i] = frag(Bs, (u32)(wn * 64 + i * 16 + ln) * 128 + ks * 64 + g * 16);
      }
#pragma unroll
      for (int i = 0; i < 4; ++i)
#pragma unroll
        for (int j = 0; j < 4; ++j)
          acc[i][j] = mfma16(af[i], bfv[j], acc[i][j]);
    }
    __syncthreads();
  }

#pragma unroll
  for (int i = 0; i < 4; ++i) {
#pragma unroll
    for (int j = 0; j < 4; ++j) {
      int e = e0 + wn * 64 + j * 16 + ln;
      int h = e >> 6, d = e & 63;
      float bias = A.bias[e];
      if (A.mode < 2) {
#pragma unroll
        for (int r = 0; r < 4; ++r) {
          int m = m0 + wm * 64 + i * 16 + g * 4 + r;
          float v = acc[i][j][r] + bias;
          int b = m >> 11, s = m & 2047;
          size_t idx = ((size_t)((b * 16 + h) * 2048 + s)) * 64 + d;
          u16 hv = f2bf(v);
          A.ohi[idx] = hv;
          A.olo[idx] = f2bf(v - bf2f(hv));
        }
      } else {
        int m = m0 + wm * 64 + i * 16 + g * 4;
        int b = m >> 11, s = m & 2047;
        u16x4 pv;
#pragma unroll
        for (int r = 0; r < 4; ++r) pv[r] = f2bf(acc[i][j][r] + bias);
        size_t idx = ((size_t)((b * 16 + h) * 64 + d)) * 2048 + s;
        *(u16x4*)(A.ohi + idx) = pv;
      }
    }
  }
}

// ---------------- attention (swapped orientation + async-STAGE T14) ----------------
__global__ __launch_bounds__(256, 3) void attn_kernel(
    const u16* __restrict__ qhi, const u16* __restrict__ qlo,
    const u16* __restrict__ khi, const u16* __restrict__ klo,
    const u16* __restrict__ vt, const int* __restrict__ amask,
    const float* __restrict__ dmask, float* __restrict__ out) {
  __shared__ u16 Ksh[64 * 64];
  __shared__ u16 Ksl[64 * 64];
  __shared__ u16 Vs[64 * 64];       // [d][k]
  __shared__ u16 Ps[4 * 16 * 64];   // per-wave [16 q][64 k]

  const int t = threadIdx.x, l = t & 63, wid = t >> 6;
  const int g = l >> 4, ln = l & 15;

  // XCD swizzle: 1024 blocks -> 128/XCD -> 4 bh per XCD (K/V L2-resident).
  int bid = blockIdx.y * 32 + blockIdx.x;
  int sid = (bid & 7) * 128 + (bid >> 3);
  const int qt = sid & 31, bh = sid >> 5, b = bh >> 4;
  const int q0 = qt * 64;
  const int qrow = q0 + wid * 16 + ln;
  const size_t qg = ((size_t)bh * 2048 + qrow) * 64;

  // Q fragments (B-operand), direct from global.
  bf16x8 qh[2], ql[2];
#pragma unroll
  for (int ks = 0; ks < 2; ++ks) {
    qh[ks] = *(const bf16x8*)(qhi + qg + ks * 32 + g * 8);
    ql[ks] = *(const bf16x8*)(qlo + qg + ks * 32 + g * 8);
  }

  // staged-tile registers (async-STAGE)
  u16x8 rkh[2], rkl[2], rv[2];
  auto load_tile = [&](int kt) {
    const int k0 = kt * 64;
    const size_t kbase = ((size_t)bh * 2048 + k0) * 64;
#pragma unroll
    for (int i = 0; i < 2; ++i) {
      int c = t + 256 * i;
      rkh[i] = *(const u16x8*)(khi + kbase + c * 8);
      rkl[i] = *(const u16x8*)(klo + kbase + c * 8);
      int row = c >> 3;
      rv[i] = *(const u16x8*)(vt + ((size_t)bh * 64 + row) * 2048 + k0 + (c & 7) * 8);
    }
  };
  auto write_tile = [&]() {
#pragma unroll
    for (int i = 0; i < 2; ++i) {
      int c = t + 256 * i;
      u32 lb = sw((u32)c * 16);
      *(u16x8*)((char*)Ksh + lb) = rkh[i];
      *(u16x8*)((char*)Ksl + lb) = rkl[i];
      *(u16x8*)((char*)Vs + lb) = rv[i];
    }
  };

  load_tile(0);
  write_tile();
  __syncthreads();

  f32x4 O[4] = {};
  float Zacc = 0.f;
  const size_t dmrow = ((size_t)bh * 2048 + qrow) * 2048;
  const u32 psbase = (u32)(wid * 2048 + ln * 128);

  for (int kt = 0; kt < 32; ++kt) {
    const int k0 = kt * 64;
    // prefetch next K/V tile into regs (in flight across the whole compute phase)
    load_tile(kt < 31 ? kt + 1 : 31);
    // dmask + pad-mask loads for this tile
    float4 dm[4]; int4 ok[4];
#pragma unroll
    for (int i = 0; i < 4; ++i) {
      dm[i] = *(const float4*)(dmask + dmrow + k0 + i * 16 + 4 * g);
      ok[i] = *(const int4*)(amask + b * 2048 + k0 + i * 16 + 4 * g);
    }

    // QK^T (3-term split): A = K rows, B = Q.
    f32x4 sc[4] = {};
#pragma unroll
    for (int ks = 0; ks < 2; ++ks) {
#pragma unroll
      for (int i = 0; i < 4; ++i) {
        u32 byt = sw((u32)((i * 16 + ln) * 128 + ks * 64 + g * 16));
        bf16x8 akh = frag(Ksh, byt);
        bf16x8 akl = frag(Ksl, byt);
        sc[i] = mfma16(akh, qh[ks], sc[i]);
        sc[i] = mfma16(akh, ql[ks], sc[i]);
        sc[i] = mfma16(akl, qh[ks], sc[i]);
      }
    }

    // pad mask -> exp -> Z -> dropout -> packed P^T write (own slab, no barrier)
#pragma unroll
    for (int i = 0; i < 4; ++i) {
      float e0 = ok[i].x ? __expf(sc[i][0]) : 0.f;
      float e1 = ok[i].y ? __expf(sc[i][1]) : 0.f;
      float e2 = ok[i].z ? __expf(sc[i][2]) : 0.f;
      float e3 = ok[i].w ? __expf(sc[i][3]) : 0.f;
      Zacc += (e0 + e1) + (e2 + e3);
      u16x4 p;
      p.x = f2bf(e0 * dm[i].x);
      p.y = f2bf(e1 * dm[i].y);
      p.z = f2bf(e2 * dm[i].z);
      p.w = f2bf(e3 * dm[i].w);
      *(u16x4*)((char*)Ps + sw(psbase + i * 32 + g * 8)) = p;
    }

    // PV: O^T = V^T . P^T
#pragma unroll
    for (int ks = 0; ks < 2; ++ks) {
      bf16x8 bP = frag(Ps, sw(psbase + ks * 64 + g * 16));
#pragma unroll
      for (int id = 0; id < 4; ++id) {
        bf16x8 aV = frag(Vs, sw((u32)((id * 16 + ln) * 128 + ks * 64 + g * 16)));
        O[id] = mfma16(aV, bP, O[id]);
      }
    }

    // swap in the prefetched tile
    __syncthreads();
    if (kt < 31) {
      write_tile();
      __syncthreads();
    }
  }

  float z = Zacc;
  z += __shfl_xor(z, 16, 64);
  z += __shfl_xor(z, 32, 64);
  float rz = 1.f / z;

#pragma unroll
  for (int id = 0; id < 4; ++id) {
    float4 o;
    o.x = O[id][0] * rz; o.y = O[id][1] * rz;
    o.z = O[id][2] * rz; o.w = O[id][3] * rz;
    *(float4*)(out + qg + id * 16 + 4 * g) = o;
  }
}

// ---------------- host ----------------
extern "C" void kernel_launch(void* const* d_in, const int* in_sizes, int n_in,
                              void* d_out, int out_size, void* d_ws, size_t ws_size,
                              hipStream_t stream) {
  const float* query = (const float*)d_in[0];
  const float* keyt  = (const float*)d_in[1];
  const float* value = (const float*)d_in[2];
  const int*   amask = (const int*)d_in[3];
  const float* dmask = (const float*)d_in[4];
  const float* Wq = (const float*)d_in[5];
  const float* bq = (const float*)d_in[6];
  const float* Wk = (const float*)d_in[7];
  const float* bk = (const float*)d_in[8];
  const float* Wv = (const float*)d_in[9];
  const float* bv = (const float*)d_in[10];

  char* ws = (char*)d_ws;
  size_t off = 0;
  auto alloc = [&](size_t bytes) {
    char* p = ws + off;
    off += (bytes + 255) & ~(size_t)255;
    return p;
  };
  const size_t XB = (size_t)MM * E_ * sizeof(u16);   // 8 MB
  const size_t WB = (size_t)E_ * E_ * sizeof(u16);   // 2 MB

  u16 *xh[3], *xl[3], *wh[3], *wl[3];
  for (int i = 0; i < 3; ++i) { xh[i] = (u16*)alloc(XB); xl[i] = (u16*)alloc(XB); }
  for (int i = 0; i < 3; ++i) { wh[i] = (u16*)alloc(WB); wl[i] = (u16*)alloc(WB); }
  u16* q_hi = (u16*)alloc(XB);
  u16* q_lo = (u16*)alloc(XB);
  u16* k_hi = (u16*)alloc(XB);
  u16* k_lo = (u16*)alloc(XB);
  u16* v_t  = (u16*)alloc(XB);
  if (off > ws_size) return;

  SplitArg sa[6] = {
      {query, xh[0], xl[0], MM * E_ / 4}, {keyt, xh[1], xl[1], MM * E_ / 4},
      {value, xh[2], xl[2], MM * E_ / 4}, {Wq, wh[0], wl[0], E_ * E_ / 4},
      {Wk, wh[1], wl[1], E_ * E_ / 4},    {Wv, wh[2], wl[2], E_ * E_ / 4},
  };
  split6_kernel<<<dim3(512, 1, 6), 256, 0, stream>>>(sa[0], sa[1], sa[2], sa[3], sa[4], sa[5]);

  ProjArgs pa[3] = {
      {xh[0], xl[0], wh[0], wl[0], bq, q_hi, q_lo, 0},
      {xh[1], xl[1], wh[1], wl[1], bk, k_hi, k_lo, 1},
      {xh[2], xl[2], wh[2], wl[2], bv, v_t, nullptr, 2},
  };
  proj_gemm<<<dim3(8, 32, 3), 256, 0, stream>>>(pa[0], pa[1], pa[2]);

  attn_kernel<<<dim3(32, 32), 256, 0, stream>>>(
      q_hi, q_lo, k_hi, k_lo, v_t, amask, dmask, (float*)d_out);
}

// Round 4
// 294.653 us; speedup vs baseline: 1.9546x; 1.0399x over previous
//
#include <hip/hip_runtime.h>

#define B_ 2
#define S_ 2048
#define E_ 1024
#define H_ 16
#define DH 64
#define MM (B_*S_)   // 4096
#define BHN (B_*H_)  // 32

typedef unsigned short u16;
typedef unsigned int u32;
typedef __attribute__((ext_vector_type(8))) __bf16 bf16x8;
typedef __attribute__((ext_vector_type(4))) float f32x4;
typedef __attribute__((ext_vector_type(8))) u16 u16x8;
typedef __attribute__((ext_vector_type(4))) u16 u16x4;

static __device__ __forceinline__ u16 f2bf(float f) {
  u32 u = __builtin_bit_cast(u32, f);
  u += 0x7fffu + ((u >> 16) & 1u);
  return (u16)(u >> 16);
}
static __device__ __forceinline__ float bf2f(u16 h) {
  return __builtin_bit_cast(float, (u32)h << 16);
}
// XOR swizzle for 128B-stride row-major LDS tiles (attn; 0 conflicts measured).
static __device__ __forceinline__ u32 sw(u32 byte) {
  return byte ^ (((byte >> 7) & 7u) << 4);
}
static __device__ __forceinline__ bf16x8 frag(const u16* lds, u32 byte) {
  return *(const bf16x8*)((const char*)lds + byte);
}
static __device__ __forceinline__ f32x4 mfma16(bf16x8 a, bf16x8 b, f32x4 c) {
  return __builtin_amdgcn_mfma_f32_16x16x32_bf16(a, b, c, 0, 0, 0);
}
static __device__ __forceinline__ void gload_lds16(const u16* g, u16* lds_base) {
  __builtin_amdgcn_global_load_lds(
      (const __attribute__((address_space(1))) u32*)g,
      (__attribute__((address_space(3))) u32*)lds_base, 16, 0, 0);
}

#define L2E 1.44269504088896340736f

// ---------------- split: f32 -> (hi, lo) bf16 ----------------
struct SplitArg { const float* s; u16* h; u16* l; int n4; };

__global__ void split6_kernel(SplitArg a0, SplitArg a1, SplitArg a2,
                              SplitArg a3, SplitArg a4, SplitArg a5) {
  SplitArg A = (blockIdx.z == 0) ? a0 : (blockIdx.z == 1) ? a1 : (blockIdx.z == 2) ? a2
             : (blockIdx.z == 3) ? a3 : (blockIdx.z == 4) ? a4 : a5;
  int i = blockIdx.x * blockDim.x + threadIdx.x;
  int stride = gridDim.x * blockDim.x;
  if (A.l) {
    for (; i < A.n4; i += stride) {
      float4 v = ((const float4*)A.s)[i];
      u16x4 h, l;
      h.x = f2bf(v.x); l.x = f2bf(v.x - bf2f(h.x));
      h.y = f2bf(v.y); l.y = f2bf(v.y - bf2f(h.y));
      h.z = f2bf(v.z); l.z = f2bf(v.z - bf2f(h.z));
      h.w = f2bf(v.w); l.w = f2bf(v.w - bf2f(h.w));
      ((u16x4*)A.h)[i] = h;
      ((u16x4*)A.l)[i] = l;
    }
  } else {  // hi-only (value: lo is never consumed)
    for (; i < A.n4; i += stride) {
      float4 v = ((const float4*)A.s)[i];
      u16x4 h;
      h.x = f2bf(v.x); h.y = f2bf(v.y); h.z = f2bf(v.z); h.w = f2bf(v.w);
      ((u16x4*)A.h)[i] = h;
    }
  }
}

// ---------------- amask -> bitmask (128 u32) ----------------
__global__ void pack_mask(const int* __restrict__ am, u32* __restrict__ pm) {
  int w = threadIdx.x;            // 0..127: [b][word]
  if (w < 128) {
    int base = (w >> 6) * 2048 + (w & 63) * 32;
    u32 bits = 0;
#pragma unroll
    for (int j = 0; j < 8; ++j) {
      int4 v = *(const int4*)(am + base + j * 4);
      bits |= (v.x ? 1u : 0u) << (4 * j) | (v.y ? 1u : 0u) << (4 * j + 1) |
              (v.z ? 1u : 0u) << (4 * j + 2) | (v.w ? 1u : 0u) << (4 * j + 3);
    }
    pm[w] = bits;
  }
}

// ---------------- projection GEMM (m97 structure) ----------------
// mode 0: Q out, scaled by log2(e), hi/lo (B,H,S,Dh). mode 1: K hi/lo.
// mode 2: bf16 V^T (B,H,Dh,S), 2-term split.
struct ProjArgs {
  const u16* xhi; const u16* xlo; const u16* whi; const u16* wlo;
  const float* bias; u16* ohi; u16* olo; int mode;
};

__global__ __launch_bounds__(256, 3) void proj_gemm(ProjArgs a0, ProjArgs a1, ProjArgs a2) {
  ProjArgs A = (blockIdx.z == 0) ? a0 : (blockIdx.z == 1) ? a1 : a2;
  __shared__ u16 As[128 * 64];
  __shared__ u16 Bs[128 * 64];
  const int t = threadIdx.x;
  const int l = t & 63, wid = t >> 6;
  const int g = l >> 4, ln = l & 15;
  const int wm = wid >> 1, wn = wid & 1;
  int bid = blockIdx.y * 8 + blockIdx.x;
  int sid = (bid & 7) * 32 + (bid >> 3);     // XCD swizzle (256 % 8 == 0)
  const int m0 = (sid >> 3) * 128, e0 = (sid & 7) * 128;

  f32x4 acc[4][4] = {};
  const int nkt = (A.mode == 2) ? 32 : 48;

  for (int kt = 0; kt < nkt; ++kt) {
    int kp = kt * 64;
    const u16* asrc = (kp < 2048) ? A.xhi : A.xlo;
    const u16* bsrc = (kp < 1024 || kp >= 2048) ? A.whi : A.wlo;
    int kc = kp & 1023;
#pragma unroll
    for (int r = 0; r < 4; ++r) {
      int cr = wid * 4 + r;
      int row = cr * 8 + (l >> 3);
      int col = (l & 7) * 8;
      gload_lds16(asrc + (size_t)(m0 + row) * 1024 + kc + col, As + cr * 512);
      gload_lds16(bsrc + (size_t)(e0 + row) * 1024 + kc + col, Bs + cr * 512);
    }
    __syncthreads();
#pragma unroll
    for (int ks = 0; ks < 2; ++ks) {
      bf16x8 af[4], bfv[4];
#pragma unroll
      for (int i = 0; i < 4; ++i) {
        af[i] = frag(As, (u32)(wm * 64 + i * 16 + ln) * 128 + ks * 64 + g * 16);
        bfv[i] = frag(Bs, (u32)(wn * 64 + i * 16 + ln) * 128 + ks * 64 + g * 16);
      }
#pragma unroll
      for (int i = 0; i < 4; ++i)
#pragma unroll
        for (int j = 0; j < 4; ++j)
          acc[i][j] = mfma16(af[i], bfv[j], acc[i][j]);
    }
    __syncthreads();
  }

#pragma unroll
  for (int i = 0; i < 4; ++i) {
#pragma unroll
    for (int j = 0; j < 4; ++j) {
      int e = e0 + wn * 64 + j * 16 + ln;
      int h = e >> 6, d = e & 63;
      float bias = A.bias[e];
      if (A.mode < 2) {
#pragma unroll
        for (int r = 0; r < 4; ++r) {
          int m = m0 + wm * 64 + i * 16 + g * 4 + r;
          float v = acc[i][j][r] + bias;
          if (A.mode == 0) v *= L2E;       // fold log2(e): attn uses exp2
          int b = m >> 11, s = m & 2047;
          size_t idx = ((size_t)((b * 16 + h) * 2048 + s)) * 64 + d;
          u16 hv = f2bf(v);
          A.ohi[idx] = hv;
          A.olo[idx] = f2bf(v - bf2f(hv));
        }
      } else {
        int m = m0 + wm * 64 + i * 16 + g * 4;
        int b = m >> 11, s = m & 2047;
        u16x4 pv;
#pragma unroll
        for (int r = 0; r < 4; ++r) pv[r] = f2bf(acc[i][j][r] + bias);
        size_t idx = ((size_t)((b * 16 + h) * 64 + d)) * 2048 + s;
        *(u16x4*)(A.ohi + idx) = pv;
      }
    }
  }
}

// ---------------- attention ----------------
// Swapped orientation (St = K.Q^T), T14 reg-staged K/V, dmask prefetched 1 tile
// ahead, pad-mask via packed bits (uniform s_loads).
__global__ __launch_bounds__(256, 3) void attn_kernel(
    const u16* __restrict__ qhi, const u16* __restrict__ qlo,
    const u16* __restrict__ khi, const u16* __restrict__ klo,
    const u16* __restrict__ vt, const u32* __restrict__ pm,
    const float* __restrict__ dmask, float* __restrict__ out) {
  __shared__ u16 Ksh[64 * 64];
  __shared__ u16 Ksl[64 * 64];
  __shared__ u16 Vs[64 * 64];       // [d][k]
  __shared__ u16 Ps[4 * 16 * 64];   // per-wave [16 q][64 k]

  const int t = threadIdx.x, l = t & 63, wid = t >> 6;
  const int g = l >> 4, ln = l & 15;

  int bid = blockIdx.y * 32 + blockIdx.x;
  int sid = (bid & 7) * 128 + (bid >> 3);   // XCD swizzle: 4 bh per XCD
  const int qt = sid & 31, bh = sid >> 5, b = bh >> 4;
  const int q0 = qt * 64;
  const int qrow = q0 + wid * 16 + ln;
  const size_t qg = ((size_t)bh * 2048 + qrow) * 64;
  const u32* pmb = pm + b * 64;

  bf16x8 qh[2], ql[2];
#pragma unroll
  for (int ks = 0; ks < 2; ++ks) {
    qh[ks] = *(const bf16x8*)(qhi + qg + ks * 32 + g * 8);
    ql[ks] = *(const bf16x8*)(qlo + qg + ks * 32 + g * 8);
  }

  const size_t dmrow = ((size_t)bh * 2048 + qrow) * 2048;
  float4 dmc[4], dmn[4];
  auto load_dm = [&](int kt, float4* d) {
    const int k0 = kt * 64;
#pragma unroll
    for (int i = 0; i < 4; ++i)
      d[i] = *(const float4*)(dmask + dmrow + k0 + i * 16 + 4 * g);
  };

  u16x8 rkh[2], rkl[2], rv[2];
  auto load_tile = [&](int kt) {
    const int k0 = kt * 64;
    const size_t kbase = ((size_t)bh * 2048 + k0) * 64;
#pragma unroll
    for (int i = 0; i < 2; ++i) {
      int c = t + 256 * i;
      rkh[i] = *(const u16x8*)(khi + kbase + c * 8);
      rkl[i] = *(const u16x8*)(klo + kbase + c * 8);
      int row = c >> 3;
      rv[i] = *(const u16x8*)(vt + ((size_t)bh * 64 + row) * 2048 + k0 + (c & 7) * 8);
    }
  };
  auto write_tile = [&]() {
#pragma unroll
    for (int i = 0; i < 2; ++i) {
      int c = t + 256 * i;
      u32 lb = sw((u32)c * 16);
      *(u16x8*)((char*)Ksh + lb) = rkh[i];
      *(u16x8*)((char*)Ksl + lb) = rkl[i];
      *(u16x8*)((char*)Vs + lb) = rv[i];
    }
  };

  load_dm(0, dmc);
  load_tile(0);
  write_tile();
  __syncthreads();

  f32x4 O[4] = {};
  float Zacc = 0.f;
  const u32 psbase = (u32)(wid * 2048 + ln * 128);

  for (int kt = 0; kt < 32; ++kt) {
    // prefetch next tile: dmask (the HBM stream) first, then K/V regs
    if (kt < 31) {
      load_dm(kt + 1, dmn);
      load_tile(kt + 1);
    }
    u32 m0 = pmb[2 * kt], m1 = pmb[2 * kt + 1];   // uniform -> s_load

    // QK^T (3-term split): A = K rows, B = Q.
    f32x4 sc[4] = {};
#pragma unroll
    for (int ks = 0; ks < 2; ++ks) {
#pragma unroll
      for (int i = 0; i < 4; ++i) {
        u32 byt = sw((u32)((i * 16 + ln) * 128 + ks * 64 + g * 16));
        bf16x8 akh = frag(Ksh, byt);
        bf16x8 akl = frag(Ksl, byt);
        sc[i] = mfma16(akh, qh[ks], sc[i]);
        sc[i] = mfma16(akh, ql[ks], sc[i]);
        sc[i] = mfma16(akl, qh[ks], sc[i]);
      }
    }

    // pad bits -> exp2 -> Z -> dropout -> packed P^T write (own slab)
#pragma unroll
    for (int i = 0; i < 4; ++i) {
      u32 mm = (i < 2 ? m0 : m1) >> (((i & 1) << 4) + 4 * g);
      float e0 = (mm & 1u) ? exp2f(sc[i][0]) : 0.f;
      float e1 = (mm & 2u) ? exp2f(sc[i][1]) : 0.f;
      float e2 = (mm & 4u) ? exp2f(sc[i][2]) : 0.f;
      float e3 = (mm & 8u) ? exp2f(sc[i][3]) : 0.f;
      Zacc += (e0 + e1) + (e2 + e3);
      u16x4 p;
      p.x = f2bf(e0 * dmc[i].x);
      p.y = f2bf(e1 * dmc[i].y);
      p.z = f2bf(e2 * dmc[i].z);
      p.w = f2bf(e3 * dmc[i].w);
      *(u16x4*)((char*)Ps + sw(psbase + i * 32 + g * 8)) = p;
    }

    // PV: O^T = V^T . P^T
#pragma unroll
    for (int ks = 0; ks < 2; ++ks) {
      bf16x8 bP = frag(Ps, sw(psbase + ks * 64 + g * 16));
#pragma unroll
      for (int id = 0; id < 4; ++id) {
        bf16x8 aV = frag(Vs, sw((u32)((id * 16 + ln) * 128 + ks * 64 + g * 16)));
        O[id] = mfma16(aV, bP, O[id]);
      }
    }

    __syncthreads();
    if (kt < 31) {
      write_tile();
      __syncthreads();
#pragma unroll
      for (int i = 0; i < 4; ++i) dmc[i] = dmn[i];
    }
  }

  float z = Zacc;
  z += __shfl_xor(z, 16, 64);
  z += __shfl_xor(z, 32, 64);
  float rz = 1.f / z;

#pragma unroll
  for (int id = 0; id < 4; ++id) {
    float4 o;
    o.x = O[id][0] * rz; o.y = O[id][1] * rz;
    o.z = O[id][2] * rz; o.w = O[id][3] * rz;
    *(float4*)(out + qg + id * 16 + 4 * g) = o;
  }
}

// ---------------- host ----------------
extern "C" void kernel_launch(void* const* d_in, const int* in_sizes, int n_in,
                              void* d_out, int out_size, void* d_ws, size_t ws_size,
                              hipStream_t stream) {
  const float* query = (const float*)d_in[0];
  const float* keyt  = (const float*)d_in[1];
  const float* value = (const float*)d_in[2];
  const int*   amask = (const int*)d_in[3];
  const float* dmask = (const float*)d_in[4];
  const float* Wq = (const float*)d_in[5];
  const float* bq = (const float*)d_in[6];
  const float* Wk = (const float*)d_in[7];
  const float* bk = (const float*)d_in[8];
  const float* Wv = (const float*)d_in[9];
  const float* bv = (const float*)d_in[10];

  char* ws = (char*)d_ws;
  size_t off = 0;
  auto alloc = [&](size_t bytes) {
    char* p = ws + off;
    off += (bytes + 255) & ~(size_t)255;
    return p;
  };
  const size_t XB = (size_t)MM * E_ * sizeof(u16);   // 8 MB
  const size_t WB = (size_t)E_ * E_ * sizeof(u16);   // 2 MB

  u16 *xh[3], *xl[3], *wh[3], *wl[3];
  for (int i = 0; i < 3; ++i) { xh[i] = (u16*)alloc(XB); xl[i] = (u16*)alloc(XB); }
  for (int i = 0; i < 3; ++i) { wh[i] = (u16*)alloc(WB); wl[i] = (u16*)alloc(WB); }
  u16* q_hi = (u16*)alloc(XB);
  u16* q_lo = (u16*)alloc(XB);
  u16* k_hi = (u16*)alloc(XB);
  u16* k_lo = (u16*)alloc(XB);
  u16* v_t  = (u16*)alloc(XB);
  u32* pmask = (u32*)alloc(512);
  if (off > ws_size) return;

  SplitArg sa[6] = {
      {query, xh[0], xl[0], MM * E_ / 4}, {keyt, xh[1], xl[1], MM * E_ / 4},
      {value, xh[2], nullptr, MM * E_ / 4}, {Wq, wh[0], wl[0], E_ * E_ / 4},
      {Wk, wh[1], wl[1], E_ * E_ / 4},    {Wv, wh[2], wl[2], E_ * E_ / 4},
  };
  split6_kernel<<<dim3(512, 1, 6), 256, 0, stream>>>(sa[0], sa[1], sa[2], sa[3], sa[4], sa[5]);
  pack_mask<<<1, 128, 0, stream>>>(amask, pmask);

  ProjArgs pa[3] = {
      {xh[0], xl[0], wh[0], wl[0], bq, q_hi, q_lo, 0},
      {xh[1], xl[1], wh[1], wl[1], bk, k_hi, k_lo, 1},
      {xh[2], nullptr, wh[2], wl[2], bv, v_t, nullptr, 2},
  };
  proj_gemm<<<dim3(8, 32, 3), 256, 0, stream>>>(pa[0], pa[1], pa[2]);

  attn_kernel<<<dim3(32, 32), 256, 0, stream>>>(
      q_hi, q_lo, k_hi, k_lo, v_t, pmask, dmask, (float*)d_out);
}